// Round 10
// baseline (183.276 us; speedup 1.0000x reference)
//
#include <hip/hip_runtime.h>
#include <hip/hip_bf16.h>

// ---------------------------------------------------------------------------
// HybridAutoEncoder on MI355X — bf16 MFMA dbuf GEMM (R4 skeleton, serial
// casts) + two changes:
//   (1) enc1 consumes w1 DIRECTLY as f32: B reg-staged (f32 load -> cvt ->
//       swizzled ds_write), double-pipelined with per-tile vmcnt groups.
//       Deletes the w1 cast kernel.
//   (2) dec3 at <128,64> grid 1024 -> 3 blocks/CU (48KB LDS dbuf).
//
//   cvt_single(x)            ~8us
//   enc1: relu(x@W1^T+b1)    gemm<128,64> REGB  grid 512   K=4096
//   cvt_triple(w2,dw2,dw3)   ~12us
//   enc2: relu(h1@W2^T+b2)   gemm<64,64>        grid 512   K=2048 (f32 out)
//   enc3+quantum+dec1 fused  (analytic latent: qz = masked cos-products)
//   dec2: relu(h3@dW2^T+db2) gemm<128,64>       grid 512   K=1024
//   dec3: h4@dW3^T+db3       gemm<128,64>       grid 1024  K=2048 (f32 out)
// ---------------------------------------------------------------------------

typedef __bf16 bf16x8 __attribute__((ext_vector_type(8)));
typedef __bf16 bf16x4 __attribute__((ext_vector_type(4)));
typedef float  f32x4  __attribute__((ext_vector_type(4)));

__device__ __forceinline__ void async16(const void* g, void* l) {
    __builtin_amdgcn_global_load_lds(
        (const __attribute__((address_space(1))) unsigned int*)g,
        (__attribute__((address_space(3))) unsigned int*)l,
        16, 0, 0);
}

template<int VM> __device__ __forceinline__ void wait_vm() {
    if constexpr (VM == 0)      asm volatile("s_waitcnt vmcnt(0) lgkmcnt(0)" ::: "memory");
    else if constexpr (VM == 4) asm volatile("s_waitcnt vmcnt(4) lgkmcnt(0)" ::: "memory");
    else if constexpr (VM == 6) asm volatile("s_waitcnt vmcnt(6) lgkmcnt(0)" ::: "memory");
    else if constexpr (VM == 8) asm volatile("s_waitcnt vmcnt(8) lgkmcnt(0)" ::: "memory");
    else static_assert(VM == 0 || VM == 4 || VM == 6 || VM == 8, "unsupported VM");
}

__device__ __forceinline__ void cvt8(const float* __restrict__ src,
                                     __bf16* __restrict__ dst, int g) {
    const float4* p = reinterpret_cast<const float4*>(src) + (size_t)g * 2;
    float4 a = p[0], b = p[1];
    bf16x8 v;
    v[0] = (__bf16)a.x; v[1] = (__bf16)a.y; v[2] = (__bf16)a.z; v[3] = (__bf16)a.w;
    v[4] = (__bf16)b.x; v[5] = (__bf16)b.y; v[6] = (__bf16)b.z; v[7] = (__bf16)b.w;
    reinterpret_cast<bf16x8*>(dst)[g] = v;
}

// C = act(A @ W^T + bias). A: MxK bf16 row-major (gload_lds staged, swizzled).
// W: NxK row-major; bf16 (gload_lds) when !REGB, f32 (reg-staged: load->cvt->
// swizzled ds_write, double-pipelined) when REGB.
// Grid 1D = GX*GY, XCD-swizzled. Dynamic LDS = 2*(BM+BN)*128 bytes.
template <int BM, int BN, int GX, int GY, typename TOUT, bool RELU, bool REGB>
__global__ __launch_bounds__(256) void gemm_pipe(
    const __bf16* __restrict__ A, const void* __restrict__ Wv,
    const float* __restrict__ bias, TOUT* __restrict__ C,
    int M, int N, int K)
{
    constexpr int CHA = BM / 32, CHB = BN / 32;
    constexpr int TOPS = REGB ? (CHA + 4) : (CHA + CHB);  // VMEM ops per tile
    constexpr int ABYTES = BM * 128, BUFB = (BM + BN) * 128;
    constexpr int WMR = BM / 2, WNC = BN / 2;
    constexpr int NI = WMR / 16, NJ = WNC / 16;
    static_assert(!REGB || BN == 64, "REGB path assumes BN==64");

    extern __shared__ char smem[];

    const int t = threadIdx.x, lane = t & 63, w = t >> 6;

    // XCD-aware bijective swizzle (GX*GY % 8 == 0); column-major decode.
    constexpr int CPX = (GX * GY) >> 3;
    const int lin = blockIdx.x;
    const int swz = (lin & 7) * CPX + (lin >> 3);
    const int bm = (swz % GY) * BM;
    const int bn = (swz / GY) * BN;

    // A staging: 8 lanes/row, XOR-swizzled source col-slot (both-sides rule)
    const int sr  = lane >> 3;
    const int scs = (lane & 7) ^ sr;
    const __bf16* gA = A + (size_t)(bm + w * 8 + sr) * K + scs * 8;

    // B staging (either path)
    const __bf16* gB = nullptr;
    const float*  gBf = nullptr;
    const int brow = w * 16 + (lane >> 2);        // REGB: local B row 0..63
    const int bx   = brow & 7;                    // REGB: row swizzle key
    const int bs0  = (lane & 3) * 2;              // REGB: first k-slot (of 8)
    if constexpr (REGB) {
        gBf = (const float*)Wv + (size_t)(bn + brow) * K + (lane & 3) * 16;
    } else {
        gB = (const __bf16*)Wv + (size_t)(bn + w * 8 + sr) * K + scs * 8;
    }

    // fragment decomposition
    const int lm = lane & 15, lh = lane >> 4;
    const int wm = w >> 1, wn = w & 1;
    const int axor = lm & 7;

    f32x4 acc[NI][NJ] = {};

    auto STAGE = [&](int buf, int tt) {           // A always; B only when !REGB
        char* la = smem + buf * BUFB + w * 1024;
        const __bf16* ga = gA + (size_t)tt * 64;
        #pragma unroll
        for (int j = 0; j < CHA; ++j) async16(ga + (size_t)32 * K * j, la + j * 4096);
        if constexpr (!REGB) {
            char* lb = smem + buf * BUFB + ABYTES + w * 1024;
            const __bf16* gb = gB + (size_t)tt * 64;
            #pragma unroll
            for (int j = 0; j < CHB; ++j) async16(gb + (size_t)32 * K * j, lb + j * 4096);
        }
    };

    auto LOADB = [&](f32x4 (&br)[4], int tt) {    // REGB: issue 4 dwordx4
        const float* g = gBf + (size_t)tt * 64;
        #pragma unroll
        for (int j = 0; j < 4; ++j) br[j] = *(const f32x4*)(g + j * 4);
    };

    auto WRITEB = [&](f32x4 (&br)[4], int buf) {  // REGB: cvt + swizzled write
        bf16x8 lo, hi;
        #pragma unroll
        for (int i = 0; i < 4; ++i) {
            lo[i] = (__bf16)br[0][i]; lo[i + 4] = (__bf16)br[1][i];
            hi[i] = (__bf16)br[2][i]; hi[i + 4] = (__bf16)br[3][i];
        }
        char* bb = smem + buf * BUFB + ABYTES + brow * 128;
        *(bf16x8*)(bb + (bs0 ^ bx) * 16)       = lo;
        *(bf16x8*)(bb + ((bs0 + 1) ^ bx) * 16) = hi;
    };

    auto COMPUTE = [&](int buf) {
        const char* base = smem + buf * BUFB;
        #pragma unroll
        for (int kh = 0; kh < 2; ++kh) {
            const int sl = ((kh * 4 + lh) ^ axor) * 16;
            bf16x8 a[NI], b[NJ];
            #pragma unroll
            for (int i = 0; i < NI; ++i)
                a[i] = *(const bf16x8*)(base + (wm * WMR + i * 16 + lm) * 128 + sl);
            #pragma unroll
            for (int j = 0; j < NJ; ++j)
                b[j] = *(const bf16x8*)(base + ABYTES + (wn * WNC + j * 16 + lm) * 128 + sl);
            __builtin_amdgcn_s_setprio(1);
            #pragma unroll
            for (int i = 0; i < NI; ++i)
                #pragma unroll
                for (int j = 0; j < NJ; ++j)
                    acc[i][j] = __builtin_amdgcn_mfma_f32_16x16x32_bf16(
                        a[i], b[j], acc[i][j], 0, 0, 0);
            __builtin_amdgcn_s_setprio(0);
        }
    };

    const int NT = K >> 6;                        // NT even for all layers here
    f32x4 brA[4], brB[4];

    // prologue — per-tile VMEM groups in FIFO order: [B(0),A(0)],[B(1),A(1)]
    if constexpr (REGB) LOADB(brA, 0);
    STAGE(0, 0);
    if constexpr (REGB) LOADB(brB, 1);
    STAGE(1, 1);

    auto ITER = [&](int tt, f32x4 (&br)[4]) {
        if (tt < NT - 1) wait_vm<TOPS>();         // tile tt fully landed
        else             wait_vm<0>();
        __builtin_amdgcn_sched_barrier(0);
        if constexpr (REGB) {
            WRITEB(br, tt & 1);
            asm volatile("s_waitcnt lgkmcnt(0)" ::: "memory");
        }
        __builtin_amdgcn_s_barrier();
        __builtin_amdgcn_sched_barrier(0);
        COMPUTE(tt & 1);
        if (tt + 2 < NT) {
            asm volatile("s_waitcnt lgkmcnt(0)" ::: "memory");
            __builtin_amdgcn_s_barrier();
            __builtin_amdgcn_sched_barrier(0);
            if constexpr (REGB) LOADB(br, tt + 2);
            STAGE(tt & 1, tt + 2);
        }
    };

    for (int tt = 0; tt < NT; tt += 2) {
        ITER(tt, brA);
        ITER(tt + 1, brB);
    }

    // epilogue
    #pragma unroll
    for (int i = 0; i < NI; ++i) {
        const int row0 = bm + wm * WMR + i * 16 + lh * 4;
        #pragma unroll
        for (int j = 0; j < NJ; ++j) {
            const int col = bn + wn * WNC + j * 16 + lm;
            const float bv = bias[col];
            #pragma unroll
            for (int r = 0; r < 4; ++r) {
                float v = acc[i][j][r] + bv;
                if (RELU) v = fmaxf(v, 0.f);
                C[(size_t)(row0 + r) * N + col] = (TOUT)v;
            }
        }
    }
}

__global__ __launch_bounds__(256) void cvt_single(
    const float* __restrict__ s, __bf16* __restrict__ d, int n)
{
    int i = blockIdx.x * 256 + threadIdx.x;
    if (i < n) cvt8(s, d, i);
}

__global__ __launch_bounds__(256) void cvt_triple(
    const float* __restrict__ s0, __bf16* __restrict__ d0, int n0,
    const float* __restrict__ s1, __bf16* __restrict__ d1, int n1,
    const float* __restrict__ s2, __bf16* __restrict__ d2)
{
    int i = blockIdx.x * 256 + threadIdx.x;
    if (i < n0)           cvt8(s0, d0, i);
    else if (i < n0 + n1) cvt8(s1, d1, i - n0);
    else                  cvt8(s2, d2, i - n0 - n1);
}

// XOR-mask of initial qubits whose cos(theta) multiply into final <Z_q>.
__constant__ unsigned short kSMask[12] = {
    0xAAB, 0xFFD, 0xFFA, 0xFF5, 0xFEA, 0xFD5,
    0xFAA, 0xF55, 0xEAA, 0xD55, 0xAAA, 0x555
};

// Fused: z = h2 @ W3^T + b3 ; qz = masked cos-products ; h3 = relu(qz@dW1^T+db1)
__global__ __launch_bounds__(256) void enc3q_dec1(
    const float* __restrict__ H2,   // 2048 x 1024 (f32)
    const float* __restrict__ W3,   // 12 x 1024
    const float* __restrict__ b3,   // 12
    const float* __restrict__ qp,   // 12
    const float* __restrict__ dW1,  // 1024 x 12
    const float* __restrict__ db1,  // 1024
    __bf16* __restrict__ H3)        // 2048 x 1024 (bf16)
{
    const int b    = blockIdx.x;
    const int t    = threadIdx.x;
    const int lane = t & 63;
    const int wid  = t >> 6;

    float h[4];
    #pragma unroll
    for (int i = 0; i < 4; ++i) h[i] = H2[(size_t)b * 1024 + t + i * 256];

    __shared__ float wred[4][12];
    __shared__ float ctheta[12];
    __shared__ float qz[12];

    #pragma unroll 1
    for (int n = 0; n < 12; ++n) {
        float p = 0.f;
        #pragma unroll
        for (int i = 0; i < 4; ++i)
            p = fmaf(h[i], W3[n * 1024 + t + i * 256], p);
        #pragma unroll
        for (int off = 32; off > 0; off >>= 1)
            p += __shfl_down(p, off);
        if (lane == 0) wred[wid][n] = p;
    }
    __syncthreads();

    if (t < 12) {
        float z = wred[0][t] + wred[1][t] + wred[2][t] + wred[3][t]
                + b3[t] + qp[t];
        ctheta[t] = cosf(z);
    }
    __syncthreads();

    if (t < 12) {
        const unsigned m = kSMask[t];
        float prod = 1.f;
        #pragma unroll
        for (int j = 0; j < 12; ++j)
            if ((m >> j) & 1) prod *= ctheta[j];
        qz[t] = prod;
    }
    __syncthreads();

    bf16x4 v;
    #pragma unroll
    for (int j = 0; j < 4; ++j) {
        const int n = t * 4 + j;
        float acc = db1[n];
        #pragma unroll
        for (int k = 0; k < 12; ++k)
            acc = fmaf(qz[k], dW1[n * 12 + k], acc);
        v[j] = (__bf16)fmaxf(acc, 0.f);
    }
    *reinterpret_cast<bf16x4*>(&H3[(size_t)b * 1024 + t * 4]) = v;
}

extern "C" void kernel_launch(void* const* d_in, const int* in_sizes, int n_in,
                              void* d_out, int out_size, void* d_ws, size_t ws_size,
                              hipStream_t stream) {
    const float* x   = (const float*)d_in[0];
    const float* w1  = (const float*)d_in[1];
    const float* b1  = (const float*)d_in[2];
    const float* w2  = (const float*)d_in[3];
    const float* b2  = (const float*)d_in[4];
    const float* w3  = (const float*)d_in[5];
    const float* b3  = (const float*)d_in[6];
    const float* qp  = (const float*)d_in[7];
    const float* dw1 = (const float*)d_in[8];
    const float* db1 = (const float*)d_in[9];
    const float* dw2 = (const float*)d_in[10];
    const float* db2 = (const float*)d_in[11];
    const float* dw3 = (const float*)d_in[12];
    const float* db3 = (const float*)d_in[13];
    float* out = (float*)d_out;

    const int B = 2048, D = 4096, H1 = 2048, H2 = 1024;

    static int attr_done = 0;
    if (!attr_done) {
        hipFuncSetAttribute((const void*)&gemm_pipe<128, 64, 32, 16, __bf16, true, true>,
                            hipFuncAttributeMaxDynamicSharedMemorySize, 49152);
        hipFuncSetAttribute((const void*)&gemm_pipe<64, 64, 16, 32, float, true, false>,
                            hipFuncAttributeMaxDynamicSharedMemorySize, 32768);
        hipFuncSetAttribute((const void*)&gemm_pipe<128, 64, 32, 16, __bf16, true, false>,
                            hipFuncAttributeMaxDynamicSharedMemorySize, 49152);
        hipFuncSetAttribute((const void*)&gemm_pipe<128, 64, 64, 16, float, false, false>,
                            hipFuncAttributeMaxDynamicSharedMemorySize, 49152);
        attr_done = 1;
    }

    // Workspace layout (bytes), serial lifetimes (R4 pattern); peak 40 MB.
    char* ws = (char*)d_ws;
    __bf16* xb   = (__bf16*)(ws);              //  0..16M   dies after enc1
    __bf16* dw3b = (__bf16*)(ws);              //  0..16M   written after enc1
    float*  h2f  = (float*) (ws + 16777216);   // 16..24M   after enc1
    __bf16* w2b  = (__bf16*)(ws + 25165824);   // 24..28M   dies after enc2
    __bf16* h3b  = (__bf16*)(ws + 25165824);   // 24..28M   after enc2
    __bf16* dw2b = (__bf16*)(ws + 29360128);   // 28..32M
    __bf16* h1b  = (__bf16*)(ws + 33554432);   // 32..40M   dies after enc2
    __bf16* h4b  = (__bf16*)(ws + 33554432);   // 32..40M   after enc2

    dim3 blk(256);

    // cast x only (w1 consumed as f32 by enc1's REGB path)
    cvt_single<<<dim3(4096), blk, 0, stream>>>(x, xb, 1048576);

    // enc1: h1 = relu(x @ w1^T + b1)   [2048x2048x4096]  REGB, grid 512
    gemm_pipe<128, 64, 32, 16, __bf16, true, true><<<dim3(512), blk, 49152, stream>>>(
        xb, w1, b1, h1b, B, H1, D);

    // casts for remaining weights (w2, dw2, dw3)
    cvt_triple<<<dim3(6144), blk, 0, stream>>>(w2, w2b, 262144,
                                               dw2, dw2b, 262144,
                                               dw3, dw3b);

    // enc2: h2 = relu(h1 @ w2^T + b2) -> f32   [2048x1024x2048]  grid 512
    gemm_pipe<64, 64, 16, 32, float, true, false><<<dim3(512), blk, 32768, stream>>>(
        h1b, w2b, b2, h2f, B, H2, H1);

    // enc3 + quantum latent + dec1
    enc3q_dec1<<<dim3(B), blk, 0, stream>>>(h2f, w3, b3, qp, dw1, db1, h3b);

    // dec2: h4 = relu(h3 @ dw2^T + db2)   [2048x2048x1024]  grid 512
    gemm_pipe<128, 64, 32, 16, __bf16, true, false><<<dim3(512), blk, 49152, stream>>>(
        h3b, dw2b, db2, h4b, B, H1, H2);

    // dec3: out = h4 @ dw3^T + db3 -> f32   [2048x4096x2048]  grid 1024, 3/CU
    gemm_pipe<128, 64, 64, 16, float, false, false><<<dim3(1024), blk, 49152, stream>>>(
        h4b, dw3b, db3, out, B, D, H1);
}

// Round 11
// 166.767 us; speedup vs baseline: 1.0990x; 1.0990x over previous
//
#include <hip/hip_runtime.h>
#include <hip/hip_bf16.h>

// ---------------------------------------------------------------------------
// HybridAutoEncoder on MI355X — bf16 MFMA dbuf GEMM. Proven-best per-layer
// configs only (R4 skeleton + R10's dec3 occupancy win):
//
//   cvt_pair(x,w1)           serial casts (R9: concurrent tail interferes;
//   cvt_triple(w2,dw2,dw3)    R5/R10: in-GEMM f32 consumption loses)
//   enc1: relu(x@W1^T+b1)    gemm<128,64>  grid 512   2/CU   K=4096
//   enc2: relu(h1@W2^T+b2)   gemm<64,64>   grid 512   2/CU   K=2048 (f32 out)
//   enc3+quantum+dec1 fused  (analytic latent: qz = masked cos-products)
//   dec2: relu(h3@dW2^T+db2) gemm<128,64>  grid 512   2/CU   K=1024
//   dec3: h4@dW3^T+db3       gemm<128,64>  grid 1024  3/CU   K=2048 (f32 out)
//
// GEMM: BK=64, 4 waves (2x2), double-buffer, both operands global_load_lds
// staged, counted vmcnt(L) at loop head, lgkmcnt(0)+barrier before re-stage,
// XOR-swizzled LDS (pre-swizzled global source + swizzled ds_read),
// setprio(1) around MFMA, XCD-aware bijective block swizzle.
// ---------------------------------------------------------------------------

typedef __bf16 bf16x8 __attribute__((ext_vector_type(8)));
typedef __bf16 bf16x4 __attribute__((ext_vector_type(4)));
typedef float  f32x4  __attribute__((ext_vector_type(4)));

__device__ __forceinline__ void async16(const void* g, void* l) {
    __builtin_amdgcn_global_load_lds(
        (const __attribute__((address_space(1))) unsigned int*)g,
        (__attribute__((address_space(3))) unsigned int*)l,
        16, 0, 0);
}

template<int VM> __device__ __forceinline__ void wait_vm() {
    if constexpr (VM == 0)      asm volatile("s_waitcnt vmcnt(0) lgkmcnt(0)" ::: "memory");
    else if constexpr (VM == 4) asm volatile("s_waitcnt vmcnt(4) lgkmcnt(0)" ::: "memory");
    else if constexpr (VM == 6) asm volatile("s_waitcnt vmcnt(6) lgkmcnt(0)" ::: "memory");
    else if constexpr (VM == 8) asm volatile("s_waitcnt vmcnt(8) lgkmcnt(0)" ::: "memory");
    else static_assert(VM == 0 || VM == 4 || VM == 6 || VM == 8, "unsupported VM");
}

__device__ __forceinline__ void cvt8(const float* __restrict__ src,
                                     __bf16* __restrict__ dst, int g) {
    const float4* p = reinterpret_cast<const float4*>(src) + (size_t)g * 2;
    float4 a = p[0], b = p[1];
    bf16x8 v;
    v[0] = (__bf16)a.x; v[1] = (__bf16)a.y; v[2] = (__bf16)a.z; v[3] = (__bf16)a.w;
    v[4] = (__bf16)b.x; v[5] = (__bf16)b.y; v[6] = (__bf16)b.z; v[7] = (__bf16)b.w;
    reinterpret_cast<bf16x8*>(dst)[g] = v;
}

// C = act(A @ W^T + bias). A: MxK bf16 row-major. W: NxK bf16 row-major.
// Grid 1D = GX*GY (XCD-swizzled). Dynamic LDS = 2*(BM+BN)*128 bytes.
template <int BM, int BN, int GX, int GY, typename TOUT, bool RELU>
__global__ __launch_bounds__(256) void gemm_pipe(
    const __bf16* __restrict__ A, const __bf16* __restrict__ W,
    const float* __restrict__ bias, TOUT* __restrict__ C,
    int M, int N, int K)
{
    constexpr int CHA = BM / 32, CHB = BN / 32, L = CHA + CHB;
    constexpr int ABYTES = BM * 128, BUFB = (BM + BN) * 128;
    constexpr int WMR = BM / 2, WNC = BN / 2;
    constexpr int NI = WMR / 16, NJ = WNC / 16;

    extern __shared__ char smem[];

    const int t = threadIdx.x, lane = t & 63, w = t >> 6;

    // XCD-aware bijective swizzle (GX*GY % 8 == 0); column-major decode so
    // each XCD owns contiguous bn-panels (weights stay L2-resident).
    constexpr int CPX = (GX * GY) >> 3;
    const int lin = blockIdx.x;
    const int swz = (lin & 7) * CPX + (lin >> 3);
    const int bm = (swz % GY) * BM;
    const int bn = (swz / GY) * BN;

    // staging: 8 lanes/row, XOR-swizzled source col-slot (both-sides rule 21)
    const int sr  = lane >> 3;
    const int scs = (lane & 7) ^ sr;
    const __bf16* gA = A + (size_t)(bm + w * 8 + sr) * K + scs * 8;
    const __bf16* gB = W + (size_t)(bn + w * 8 + sr) * K + scs * 8;

    // fragment decomposition
    const int lm = lane & 15, lh = lane >> 4;
    const int wm = w >> 1, wn = w & 1;
    const int axor = lm & 7;

    f32x4 acc[NI][NJ] = {};

    auto STAGE = [&](int buf, int tt) {
        char* la = smem + buf * BUFB + w * 1024;
        char* lb = smem + buf * BUFB + ABYTES + w * 1024;
        const __bf16* ga = gA + (size_t)tt * 64;
        const __bf16* gb = gB + (size_t)tt * 64;
        #pragma unroll
        for (int j = 0; j < CHA; ++j) async16(ga + (size_t)32 * K * j, la + j * 4096);
        #pragma unroll
        for (int j = 0; j < CHB; ++j) async16(gb + (size_t)32 * K * j, lb + j * 4096);
    };

    auto COMPUTE = [&](int buf) {
        const char* base = smem + buf * BUFB;
        #pragma unroll
        for (int kh = 0; kh < 2; ++kh) {
            const int sl = ((kh * 4 + lh) ^ axor) * 16;
            bf16x8 a[NI], b[NJ];
            #pragma unroll
            for (int i = 0; i < NI; ++i)
                a[i] = *(const bf16x8*)(base + (wm * WMR + i * 16 + lm) * 128 + sl);
            #pragma unroll
            for (int j = 0; j < NJ; ++j)
                b[j] = *(const bf16x8*)(base + ABYTES + (wn * WNC + j * 16 + lm) * 128 + sl);
            __builtin_amdgcn_s_setprio(1);
            #pragma unroll
            for (int i = 0; i < NI; ++i)
                #pragma unroll
                for (int j = 0; j < NJ; ++j)
                    acc[i][j] = __builtin_amdgcn_mfma_f32_16x16x32_bf16(
                        a[i], b[j], acc[i][j], 0, 0, 0);
            __builtin_amdgcn_s_setprio(0);
        }
    };

    const int NT = K >> 6;
    STAGE(0, 0);
    STAGE(1, 1);

    for (int tt = 0; tt < NT; ++tt) {
        if (tt < NT - 1) wait_vm<L>();
        else             wait_vm<0>();
        __builtin_amdgcn_s_barrier();
        __builtin_amdgcn_sched_barrier(0);
        COMPUTE(tt & 1);
        if (tt + 2 < NT) {
            asm volatile("s_waitcnt lgkmcnt(0)" ::: "memory");
            __builtin_amdgcn_s_barrier();
            __builtin_amdgcn_sched_barrier(0);
            STAGE(tt & 1, tt + 2);
        }
    }

    // epilogue
    #pragma unroll
    for (int i = 0; i < NI; ++i) {
        const int row0 = bm + wm * WMR + i * 16 + lh * 4;
        #pragma unroll
        for (int j = 0; j < NJ; ++j) {
            const int col = bn + wn * WNC + j * 16 + lm;
            const float bv = bias[col];
            #pragma unroll
            for (int r = 0; r < 4; ++r) {
                float v = acc[i][j][r] + bv;
                if (RELU) v = fmaxf(v, 0.f);
                C[(size_t)(row0 + r) * N + col] = (TOUT)v;
            }
        }
    }
}

__global__ __launch_bounds__(256) void cvt_pair(
    const float* __restrict__ s0, __bf16* __restrict__ d0, int n0,
    const float* __restrict__ s1, __bf16* __restrict__ d1)
{
    int i = blockIdx.x * 256 + threadIdx.x;
    if (i < n0) cvt8(s0, d0, i);
    else        cvt8(s1, d1, i - n0);
}

__global__ __launch_bounds__(256) void cvt_triple(
    const float* __restrict__ s0, __bf16* __restrict__ d0, int n0,
    const float* __restrict__ s1, __bf16* __restrict__ d1, int n1,
    const float* __restrict__ s2, __bf16* __restrict__ d2)
{
    int i = blockIdx.x * 256 + threadIdx.x;
    if (i < n0)           cvt8(s0, d0, i);
    else if (i < n0 + n1) cvt8(s1, d1, i - n0);
    else                  cvt8(s2, d2, i - n0 - n1);
}

// XOR-mask of initial qubits whose cos(theta) multiply into final <Z_q>.
__constant__ unsigned short kSMask[12] = {
    0xAAB, 0xFFD, 0xFFA, 0xFF5, 0xFEA, 0xFD5,
    0xFAA, 0xF55, 0xEAA, 0xD55, 0xAAA, 0x555
};

// Fused: z = h2 @ W3^T + b3 ; qz = masked cos-products ; h3 = relu(qz@dW1^T+db1)
__global__ __launch_bounds__(256) void enc3q_dec1(
    const float* __restrict__ H2,   // 2048 x 1024 (f32)
    const float* __restrict__ W3,   // 12 x 1024
    const float* __restrict__ b3,   // 12
    const float* __restrict__ qp,   // 12
    const float* __restrict__ dW1,  // 1024 x 12
    const float* __restrict__ db1,  // 1024
    __bf16* __restrict__ H3)        // 2048 x 1024 (bf16)
{
    const int b    = blockIdx.x;
    const int t    = threadIdx.x;
    const int lane = t & 63;
    const int wid  = t >> 6;

    float h[4];
    #pragma unroll
    for (int i = 0; i < 4; ++i) h[i] = H2[(size_t)b * 1024 + t + i * 256];

    __shared__ float wred[4][12];
    __shared__ float ctheta[12];
    __shared__ float qz[12];

    #pragma unroll 1
    for (int n = 0; n < 12; ++n) {
        float p = 0.f;
        #pragma unroll
        for (int i = 0; i < 4; ++i)
            p = fmaf(h[i], W3[n * 1024 + t + i * 256], p);
        #pragma unroll
        for (int off = 32; off > 0; off >>= 1)
            p += __shfl_down(p, off);
        if (lane == 0) wred[wid][n] = p;
    }
    __syncthreads();

    if (t < 12) {
        float z = wred[0][t] + wred[1][t] + wred[2][t] + wred[3][t]
                + b3[t] + qp[t];
        ctheta[t] = cosf(z);
    }
    __syncthreads();

    if (t < 12) {
        const unsigned m = kSMask[t];
        float prod = 1.f;
        #pragma unroll
        for (int j = 0; j < 12; ++j)
            if ((m >> j) & 1) prod *= ctheta[j];
        qz[t] = prod;
    }
    __syncthreads();

    bf16x4 v;
    #pragma unroll
    for (int j = 0; j < 4; ++j) {
        const int n = t * 4 + j;
        float acc = db1[n];
        #pragma unroll
        for (int k = 0; k < 12; ++k)
            acc = fmaf(qz[k], dW1[n * 12 + k], acc);
        v[j] = (__bf16)fmaxf(acc, 0.f);
    }
    *reinterpret_cast<bf16x4*>(&H3[(size_t)b * 1024 + t * 4]) = v;
}

extern "C" void kernel_launch(void* const* d_in, const int* in_sizes, int n_in,
                              void* d_out, int out_size, void* d_ws, size_t ws_size,
                              hipStream_t stream) {
    const float* x   = (const float*)d_in[0];
    const float* w1  = (const float*)d_in[1];
    const float* b1  = (const float*)d_in[2];
    const float* w2  = (const float*)d_in[3];
    const float* b2  = (const float*)d_in[4];
    const float* w3  = (const float*)d_in[5];
    const float* b3  = (const float*)d_in[6];
    const float* qp  = (const float*)d_in[7];
    const float* dw1 = (const float*)d_in[8];
    const float* db1 = (const float*)d_in[9];
    const float* dw2 = (const float*)d_in[10];
    const float* db2 = (const float*)d_in[11];
    const float* dw3 = (const float*)d_in[12];
    const float* db3 = (const float*)d_in[13];
    float* out = (float*)d_out;

    const int B = 2048, D = 4096, H1 = 2048, H2 = 1024;

    static int attr_done = 0;
    if (!attr_done) {
        hipFuncSetAttribute((const void*)&gemm_pipe<128, 64, 32, 16, __bf16, true>,
                            hipFuncAttributeMaxDynamicSharedMemorySize, 49152);
        hipFuncSetAttribute((const void*)&gemm_pipe<64, 64, 16, 32, float, true>,
                            hipFuncAttributeMaxDynamicSharedMemorySize, 32768);
        hipFuncSetAttribute((const void*)&gemm_pipe<128, 64, 64, 16, float, false>,
                            hipFuncAttributeMaxDynamicSharedMemorySize, 49152);
        attr_done = 1;
    }

    // Workspace layout (bytes), serial lifetimes (R4 pattern); peak 40 MB.
    char* ws = (char*)d_ws;
    __bf16* xb   = (__bf16*)(ws);              //  0..16M   dies after enc1
    __bf16* dw3b = (__bf16*)(ws);              //  0..16M   written after enc1
    __bf16* w1b  = (__bf16*)(ws + 16777216);   // 16..32M   dies after enc1
    float*  h2f  = (float*) (ws + 16777216);   // 16..24M   after enc1
    __bf16* w2b  = (__bf16*)(ws + 25165824);   // 24..28M   dies after enc2
    __bf16* h3b  = (__bf16*)(ws + 25165824);   // 24..28M   after enc2
    __bf16* dw2b = (__bf16*)(ws + 29360128);   // 28..32M
    __bf16* h1b  = (__bf16*)(ws + 33554432);   // 32..40M   dies after enc2
    __bf16* h4b  = (__bf16*)(ws + 33554432);   // 32..40M   after enc2

    dim3 blk(256);

    // casts for enc1 inputs (x, w1)
    cvt_pair<<<dim3(8192), blk, 0, stream>>>(x, xb, 1048576, w1, w1b);

    // enc1: h1 = relu(x @ w1^T + b1)   [2048x2048x4096]  grid 512, 2/CU
    gemm_pipe<128, 64, 32, 16, __bf16, true><<<dim3(512), blk, 49152, stream>>>(
        xb, w1b, b1, h1b, B, H1, D);

    // casts for remaining weights (w2, dw2, dw3)
    cvt_triple<<<dim3(6144), blk, 0, stream>>>(w2, w2b, 262144,
                                               dw2, dw2b, 262144,
                                               dw3, dw3b);

    // enc2: h2 = relu(h1 @ w2^T + b2) -> f32   [2048x1024x2048]  grid 512
    gemm_pipe<64, 64, 16, 32, float, true><<<dim3(512), blk, 32768, stream>>>(
        h1b, w2b, b2, h2f, B, H2, H1);

    // enc3 + quantum latent + dec1
    enc3q_dec1<<<dim3(B), blk, 0, stream>>>(h2f, w3, b3, qp, dw1, db1, h3b);

    // dec2: h4 = relu(h3 @ dw2^T + db2)   [2048x2048x1024]  grid 512
    gemm_pipe<128, 64, 32, 16, __bf16, true><<<dim3(512), blk, 49152, stream>>>(
        h3b, dw2b, db2, h4b, B, H1, H2);

    // dec3: out = h4 @ dw3^T + db3 -> f32   [2048x4096x2048]  grid 1024, 3/CU
    gemm_pipe<128, 64, 64, 16, float, false><<<dim3(1024), blk, 49152, stream>>>(
        h4b, dw3b, db3, out, B, D, H1);
}